// Round 9
// baseline (498.856 us; speedup 1.0000x reference)
//
#include <hip/hip_runtime.h>
#include <stdint.h>

#define C_HID 128
#define NGRAPH 64
#define COUT 64
#define NBLK 256      // edge-chunk blocks for cnt/scat
#define BKT 256       // nodes per bucket
#define NBUK_MAX 512
typedef short bf16x8 __attribute__((ext_vector_type(8)));
typedef float f32x4 __attribute__((ext_vector_type(4)));
typedef float f32x2 __attribute__((ext_vector_type(2)));

__device__ __forceinline__ unsigned short f2bf(float f){
  unsigned int u = __builtin_bit_cast(unsigned int, f);
  u = u + 0x7FFFu + ((u >> 16) & 1u);   // RNE
  return (unsigned short)(u >> 16);
}
__device__ __forceinline__ int clampi(int v, int lo, int hi){
  return v < lo ? lo : (v > hi ? hi : v);
}

__global__ void k_zero(float* __restrict__ out, int n){
  int i = blockIdx.x*blockDim.x + threadIdx.x;
  if (i < n) out[i] = 0.f;
}

// ---------- CSR pass 1: bucket totals (LDS hist + 1 global add per (block,bucket));
// last block (done-counter) scans totals in-LDS -> bases[0..NBUK] and cur[] ----------
__global__ __launch_bounds__(256) void k_cnt(const int* __restrict__ dst,
                                             int* __restrict__ bcnt,   // [NBUK_MAX], zeroed
                                             int* __restrict__ done1,  // zeroed
                                             int* __restrict__ bases,  // [NBUK_MAX+1]
                                             int* __restrict__ cur,    // [NBUK_MAX]
                                             int E, int N, int NBUK, int chunk){
  __shared__ int cnt[NBUK_MAX];
  __shared__ int amLast;
  int t = threadIdx.x;
  for (int b = t; b < NBUK; b += 256) cnt[b] = 0;
  __syncthreads();
  int e0 = blockIdx.x*chunk, e1 = min(E, e0 + chunk);
  for (int e = e0 + t; e < e1; e += 256)
    atomicAdd(&cnt[clampi(dst[e], 0, N-1) >> 8], 1);
  __syncthreads();
  for (int b = t; b < NBUK; b += 256)
    if (cnt[b]) atomicAdd(&bcnt[b], cnt[b]);
  __threadfence();
  if (t == 0){
    int old = __hip_atomic_fetch_add(done1, 1, __ATOMIC_ACQ_REL, __HIP_MEMORY_SCOPE_AGENT);
    amLast = (old == (int)gridDim.x - 1);
  }
  __syncthreads();
  if (!amLast) return;

  // last block: exclusive scan of 512 (zero-padded) totals with 256 threads
  __shared__ int sb[512];
  int a0 = __hip_atomic_load(&bcnt[t],       __ATOMIC_RELAXED, __HIP_MEMORY_SCOPE_AGENT);
  int a1 = __hip_atomic_load(&bcnt[t + 256], __ATOMIC_RELAXED, __HIP_MEMORY_SCOPE_AGENT);
  sb[t] = a0; sb[t + 256] = a1;
  __syncthreads();
  for (int off = 1; off < 256; off <<= 1){
    int x0 = (t >= off) ? sb[t - off] : 0;
    int x1 = (t >= off) ? sb[256 + t - off] : 0;
    __syncthreads();
    sb[t] += x0; sb[256 + t] += x1;
    __syncthreads();
  }
  int lowTot = sb[255];
  sb[256 + t] += lowTot;
  __syncthreads();
  bases[t]       = sb[t] - a0;        cur[t]       = sb[t] - a0;
  bases[t + 256] = sb[t + 256] - a1;  cur[t + 256] = sb[t + 256] - a1;
  if (t == 255) bases[512] = sb[511];   // harmless; bases sized NBUK_MAX+1
  // bases[NBUK] is a written slot (NBUK<=512) and equals E (zero-padded tail)
}

// ---------- CSR pass 2: local count -> reserve segment (atomicAdd cur) -> scatter ----
__global__ __launch_bounds__(256) void k_scat(const int* __restrict__ src,
                                              const int* __restrict__ dst,
                                              int* __restrict__ cur,
                                              unsigned int* __restrict__ rec,
                                              int E, int N, int NBUK, int chunk){
  __shared__ int cnt[NBUK_MAX];
  __shared__ int lbase[NBUK_MAX];
  int t = threadIdx.x;
  for (int b = t; b < NBUK; b += 256) cnt[b] = 0;
  __syncthreads();
  int e0 = blockIdx.x*chunk, e1 = min(E, e0 + chunk);
  for (int e = e0 + t; e < e1; e += 256)
    atomicAdd(&cnt[clampi(dst[e], 0, N-1) >> 8], 1);
  __syncthreads();
  for (int b = t; b < NBUK; b += 256)
    lbase[b] = cnt[b] ? atomicAdd(&cur[b], cnt[b]) : 0;
  __syncthreads();
  for (int b = t; b < NBUK; b += 256) cnt[b] = 0;   // reuse as local cursor
  __syncthreads();
  for (int e = e0 + t; e < e1; e += 256){
    int d = clampi(dst[e], 0, N-1);
    int s = clampi(src[e], 0, N-1);
    int b = d >> 8;
    int p = lbase[b] + atomicAdd(&cnt[b], 1);
    rec[p] = (unsigned int)s | ((unsigned int)(d & 255) << 24);
  }
}

// ---------- CSR pass 3: per-bucket local CSR (offs, dinv, meta) ----------
__global__ __launch_bounds__(256) void k_csr(const unsigned int* __restrict__ rec,
                                             const int* __restrict__ bases,
                                             int* __restrict__ offs, float* __restrict__ dinv,
                                             int* __restrict__ meta, int E, int N, int NBUK){
  __shared__ int cnt[BKT], loff[BKT], cur[BKT];
  int b = blockIdx.x, t = threadIdx.x;
  cnt[t] = 0;
  __syncthreads();
  int r0 = bases[b];
  int r1 = bases[b + 1];
  for (int i = r0 + t; i < r1; i += 256)
    atomicAdd(&cnt[rec[i] >> 24], 1);
  __syncthreads();
  loff[t] = cnt[t];
  __syncthreads();
  for (int off = 1; off < BKT; off <<= 1){
    int add = (t >= off) ? loff[t - off] : 0;
    __syncthreads();
    loff[t] += add;
    __syncthreads();
  }
  int excl = loff[t] - cnt[t];
  cur[t] = r0 + excl;
  int node = b*BKT + t;
  if (node < N){
    offs[node] = r0 + excl;
    dinv[node] = rsqrtf((float)(cnt[t] + 1));   // +1 = self loop
  }
  if (b == NBUK-1 && t == 0) offs[N] = E;
  __syncthreads();
  for (int i = r0 + t; i < r1; i += 256){
    unsigned int r = rec[i];
    int p = atomicAdd(&cur[r >> 24], 1);
    meta[p] = (int)(r & 0x00FFFFFFu);
  }
}

// ---------- merged: xcast (y0 = fp8(64*dinv*x0)) + W prep + zero gsum/done3 ----------
__global__ void k_prepx(const float2* __restrict__ x, const float* __restrict__ dinv,
                        unsigned short* __restrict__ y, unsigned short* __restrict__ y2,
                        const float* __restrict__ W1, const float* __restrict__ W2,
                        const float* __restrict__ W3, unsigned short* __restrict__ Wt,
                        float* __restrict__ gsum, int* __restrict__ done3, int N){
  int i = blockIdx.x*256 + threadIdx.x;
  int tot = N*64;
  if (i < tot){
    float2 v = x[i];
    float dn = dinv[i >> 6] * 64.f;
    int p = __builtin_amdgcn_cvt_pk_fp8_f32(v.x*dn, v.y*dn, 0, false);
    y[i] = (unsigned short)(p & 0xFFFF);
  } else if (i < tot + 64){
    y[i] = 0;                       // zero row at index N (gather sink)
    y2[i] = 0;
  }
  if (i < 3*16384){
    int w = i >> 14;
    int r = i & 16383;
    int n = r & 127, k = r >> 7;
    const float* W = (w == 0) ? W1 : (w == 1) ? W2 : W3;
    Wt[(size_t)w*16384 + (size_t)n*128 + k] = f2bf(W[k*128 + n]);
  }
  if (i < NGRAPH*C_HID) gsum[i] = 0.f;
  if (i == 0) *done3 = 0;
}

// ---------- SpMM v6 (unchanged): 8 nodes/wave, at its L2-duplication service floor ----
__global__ __launch_bounds__(256) void k_spmm(const unsigned short* __restrict__ y,
                       const int* __restrict__ offs,
                       const float* __restrict__ dinv,
                       const int* __restrict__ meta,
                       unsigned int* __restrict__ agg, int N){
  int wv   = __builtin_amdgcn_readfirstlane(threadIdx.x >> 6);
  int lane = threadIdx.x & 63;
  int g = lane >> 3, c = lane & 7;
  int node0 = blockIdx.x*32 + wv*8;
  if (node0 >= N) return;

  int e[9];
  #pragma unroll
  for (int i = 0; i < 9; ++i) e[i] = offs[min(node0 + i, N)];
  int cn[8]; int maxc = 0;
  #pragma unroll
  for (int i = 0; i < 8; ++i){ cn[i] = e[i+1] - e[i]; maxc = max(maxc, cn[i]); }

  int e0l = e[0], cntl = cn[0];
  #pragma unroll
  for (int i = 1; i < 8; ++i){
    e0l  = (g == i) ? e[i]  : e0l;
    cntl = (g == i) ? cn[i] : cntl;
  }
  int nodeg = node0 + g;
  bool nok = nodeg < N;
  int nself = nok ? nodeg : N;              // row N = zero row

  const uint4* yrow = (const uint4*)y;      // row = 8 x 16B

  int mv0 = (c      < cntl) ? meta[e0l + c]      : N;
  int mv1 = (c +  8 < cntl) ? meta[e0l + c +  8] : N;
  int mv2 = (c + 16 < cntl) ? meta[e0l + c + 16] : N;
  int mv3 = (c + 24 < cntl) ? meta[e0l + c + 24] : N;
  uint4 us = yrow[(size_t)nself*8 + c];     // self row
  float dl = dinv[nok ? nodeg : 0];

  f32x2 acc[8];
  { f32x2 f;
    f = __builtin_amdgcn_cvt_pk_f32_fp8((int)us.x, false); acc[0] = f;
    f = __builtin_amdgcn_cvt_pk_f32_fp8((int)us.x, true);  acc[1] = f;
    f = __builtin_amdgcn_cvt_pk_f32_fp8((int)us.y, false); acc[2] = f;
    f = __builtin_amdgcn_cvt_pk_f32_fp8((int)us.y, true);  acc[3] = f;
    f = __builtin_amdgcn_cvt_pk_f32_fp8((int)us.z, false); acc[4] = f;
    f = __builtin_amdgcn_cvt_pk_f32_fp8((int)us.z, true);  acc[5] = f;
    f = __builtin_amdgcn_cvt_pk_f32_fp8((int)us.w, false); acc[6] = f;
    f = __builtin_amdgcn_cvt_pk_f32_fp8((int)us.w, true);  acc[7] = f; }

  uint4 u[8];
#define SWZ(MV, J) __builtin_amdgcn_ds_swizzle(MV, (0x18 | (((J)&7)<<5)))
#define GA(K, SM) u[K] = yrow[(size_t)(unsigned)(SM)*8 + c]
#define CONV8() do{ _Pragma("unroll") \
  for (int k2 = 0; k2 < 8; ++k2){ \
    f32x2 f; \
    f = __builtin_amdgcn_cvt_pk_f32_fp8((int)u[k2].x, false); acc[0] += f; \
    f = __builtin_amdgcn_cvt_pk_f32_fp8((int)u[k2].x, true);  acc[1] += f; \
    f = __builtin_amdgcn_cvt_pk_f32_fp8((int)u[k2].y, false); acc[2] += f; \
    f = __builtin_amdgcn_cvt_pk_f32_fp8((int)u[k2].y, true);  acc[3] += f; \
    f = __builtin_amdgcn_cvt_pk_f32_fp8((int)u[k2].z, false); acc[4] += f; \
    f = __builtin_amdgcn_cvt_pk_f32_fp8((int)u[k2].z, true);  acc[5] += f; \
    f = __builtin_amdgcn_cvt_pk_f32_fp8((int)u[k2].w, false); acc[6] += f; \
    f = __builtin_amdgcn_cvt_pk_f32_fp8((int)u[k2].w, true);  acc[7] += f; } }while(0)

  if (0 < maxc){
    GA(0,SWZ(mv0,0)); GA(1,SWZ(mv0,1)); GA(2,SWZ(mv0,2)); GA(3,SWZ(mv0,3));
    GA(4,SWZ(mv0,4)); GA(5,SWZ(mv0,5)); GA(6,SWZ(mv0,6)); GA(7,SWZ(mv0,7));
    __builtin_amdgcn_sched_barrier(0);
    CONV8();
  }
  if (8 < maxc){
    GA(0,SWZ(mv1,0)); GA(1,SWZ(mv1,1)); GA(2,SWZ(mv1,2)); GA(3,SWZ(mv1,3));
    GA(4,SWZ(mv1,4)); GA(5,SWZ(mv1,5)); GA(6,SWZ(mv1,6)); GA(7,SWZ(mv1,7));
    __builtin_amdgcn_sched_barrier(0);
    CONV8();
  }
  if (16 < maxc){
    GA(0,SWZ(mv2,0)); GA(1,SWZ(mv2,1)); GA(2,SWZ(mv2,2)); GA(3,SWZ(mv2,3));
    GA(4,SWZ(mv2,4)); GA(5,SWZ(mv2,5)); GA(6,SWZ(mv2,6)); GA(7,SWZ(mv2,7));
    __builtin_amdgcn_sched_barrier(0);
    CONV8();
  }
  if (24 < maxc){
    GA(0,SWZ(mv3,0)); GA(1,SWZ(mv3,1)); GA(2,SWZ(mv3,2)); GA(3,SWZ(mv3,3));
    GA(4,SWZ(mv3,4)); GA(5,SWZ(mv3,5)); GA(6,SWZ(mv3,6)); GA(7,SWZ(mv3,7));
    __builtin_amdgcn_sched_barrier(0);
    CONV8();
  }
#undef SWZ
#undef GA
#undef CONV8

  for (int j = 32; j < maxc; ++j){
    int sm = (j < cntl) ? meta[e0l + j] : N;
    uint4 t = yrow[(size_t)(unsigned)sm*8 + c];
    f32x2 f;
    f = __builtin_amdgcn_cvt_pk_f32_fp8((int)t.x, false); acc[0] += f;
    f = __builtin_amdgcn_cvt_pk_f32_fp8((int)t.x, true);  acc[1] += f;
    f = __builtin_amdgcn_cvt_pk_f32_fp8((int)t.y, false); acc[2] += f;
    f = __builtin_amdgcn_cvt_pk_f32_fp8((int)t.y, true);  acc[3] += f;
    f = __builtin_amdgcn_cvt_pk_f32_fp8((int)t.z, false); acc[4] += f;
    f = __builtin_amdgcn_cvt_pk_f32_fp8((int)t.z, true);  acc[5] += f;
    f = __builtin_amdgcn_cvt_pk_f32_fp8((int)t.w, false); acc[6] += f;
    f = __builtin_amdgcn_cvt_pk_f32_fp8((int)t.w, true);  acc[7] += f;
  }

  float dn = dl * 0.015625f;   // /64
  if (nok){
    uint4 w0, w1;
    w0.x = (unsigned int)f2bf(acc[0].x*dn) | ((unsigned int)f2bf(acc[0].y*dn) << 16);
    w0.y = (unsigned int)f2bf(acc[1].x*dn) | ((unsigned int)f2bf(acc[1].y*dn) << 16);
    w0.z = (unsigned int)f2bf(acc[2].x*dn) | ((unsigned int)f2bf(acc[2].y*dn) << 16);
    w0.w = (unsigned int)f2bf(acc[3].x*dn) | ((unsigned int)f2bf(acc[3].y*dn) << 16);
    w1.x = (unsigned int)f2bf(acc[4].x*dn) | ((unsigned int)f2bf(acc[4].y*dn) << 16);
    w1.y = (unsigned int)f2bf(acc[5].x*dn) | ((unsigned int)f2bf(acc[5].y*dn) << 16);
    w1.z = (unsigned int)f2bf(acc[6].x*dn) | ((unsigned int)f2bf(acc[6].y*dn) << 16);
    w1.w = (unsigned int)f2bf(acc[7].x*dn) | ((unsigned int)f2bf(acc[7].y*dn) << 16);
    *(uint4*)(agg + (size_t)nodeg*64 + c*8)     = w0;
    *(uint4*)(agg + (size_t)nodeg*64 + c*8 + 4) = w1;
  }
}

// ---------- GEMM: h = relu(A@W + b); FP8OUT -> fp8 y'; POOL -> gsum atomics; ----------
// POOL also folds the final (gsum/cnt @ Wlin + blin) into the LAST block via a
// device done-counter (agent scope): last block stages gsum into the dead wt LDS
// (agent atomic loads) and writes out[64][64]. Saves the k_fin dispatch.
__device__ __forceinline__ int lower_bound_i(const int* arr, int n, int val){
  int lo = 0, hi = n;
  while (lo < hi){ int mid = (lo + hi) >> 1; if (arr[mid] < val) lo = mid + 1; else hi = mid; }
  return lo;
}

#define GEMM_BLOCKS 512
template<bool FP8OUT, bool POOL>
__global__ __launch_bounds__(256) void k_gemm(const unsigned short* __restrict__ A,
                                              const unsigned short* __restrict__ Wt,
                                              const float* __restrict__ bias,
                                              const float* __restrict__ scale,
                                              void* __restrict__ outv,
                                              const int* __restrict__ batch,
                                              float* __restrict__ gsum,
                                              int* __restrict__ done3,
                                              const float* __restrict__ Wl,
                                              const float* __restrict__ bl,
                                              float* __restrict__ fout, int M){
  __shared__ unsigned short wt[128*136];
  __shared__ float gbuf[2][C_HID];
  __shared__ int amLast;
  {
    const uint4* wsrc = (const uint4*)Wt;     // 4096 uint4 (8 shorts each)
    for (int i = threadIdx.x; i < 4096; i += 256){
      uint4 v = wsrc[i];
      int n = i >> 4, kblk = i & 15;          // row = 16 uint4
      *(uint4*)&wt[n*136 + kblk*8] = v;
    }
  }
  __syncthreads();

  int wv = threadIdx.x >> 6, lane = threadIdx.x & 63;
  int q = lane >> 4, ln = lane & 15;
  int tiles = (M + 63) >> 6;

  for (int tile = blockIdx.x; tile < tiles; tile += GEMM_BLOCKS){
    int m0 = tile*64 + wv*16;
    int arow = m0 + ln;
    bool arow_ok = (arow < M);
    int arow_s = arow_ok ? arow : 0;

    f32x4 zero = {0.f, 0.f, 0.f, 0.f};
    f32x4 acc[8];
    #pragma unroll
    for (int t = 0; t < 8; ++t) acc[t] = zero;

    #pragma unroll
    for (int kk = 0; kk < 4; ++kk){
      bf16x8 a;
      if (arow_ok){
        __builtin_memcpy(&a, A + (size_t)arow_s*128 + kk*32 + q*8, 16);
      } else {
        a = (bf16x8){0,0,0,0,0,0,0,0};
      }
      #pragma unroll
      for (int t = 0; t < 8; ++t){
        bf16x8 b;
        __builtin_memcpy(&b, &wt[(t*16 + ln)*136 + kk*32 + q*8], 16);
        acc[t] = __builtin_amdgcn_mfma_f32_16x16x32_bf16(a, b, acc[t], 0, 0, 0);
      }
    }

    if (POOL){
      int tb = tile*64;
      int gA = batch[tb];
      int gB = batch[min(tb + 63, M - 1)];
      bool multi = (gB > gA + 1);             // defensive; ~impossible
      __syncthreads();                        // prior tile's gbuf flush done
      ((float*)gbuf)[threadIdx.x] = 0.f;      // 256 slots = 2 x 128
      __syncthreads();
      #pragma unroll
      for (int t = 0; t < 8; ++t){
        float bv = bias[t*16 + ln];
        int ch = t*16 + ln;
        float s0 = 0.f, s1 = 0.f;
        #pragma unroll
        for (int r = 0; r < 4; ++r){
          int row = m0 + q*4 + r;
          if (row < M){
            float v = acc[t][r] + bv;
            v = v > 0.f ? v : 0.f;
            if (multi){
              atomicAdd(&gsum[(size_t)batch[row]*C_HID + ch], v);
            } else if (gB > gA && batch[row] != gA){
              s1 += v;
            } else {
              s0 += v;
            }
          }
        }
        if (!multi){
          if (s0 != 0.f) atomicAdd(&gbuf[0][ch], s0);
          if (s1 != 0.f) atomicAdd(&gbuf[1][ch], s1);
        }
      }
      __syncthreads();
      if (!multi){
        int sel = threadIdx.x >> 7, ch2 = threadIdx.x & 127;
        if (sel == 0 || gB > gA){
          float v = ((float*)gbuf)[threadIdx.x];
          if (v != 0.f)
            atomicAdd(&gsum[(size_t)((sel == 0) ? gA : gB)*C_HID + ch2], v);
        }
      }
    } else {
      float sc[4];
      #pragma unroll
      for (int r = 0; r < 4; ++r){
        int row = m0 + q*4 + r;
        sc[r] = (FP8OUT && row < M) ? scale[row] * 64.f : 1.0f;
      }
      #pragma unroll
      for (int t = 0; t < 8; ++t){
        float bv = bias[t*16 + ln];
        #pragma unroll
        for (int r = 0; r < 4; ++r){
          int row = m0 + q*4 + r;
          if (row < M){
            float v = acc[t][r] + bv;
            v = v > 0.f ? v : 0.f;
            if (FP8OUT){
              v *= sc[r];
              int p = __builtin_amdgcn_cvt_pk_fp8_f32(v, v, 0, false);
              ((unsigned char*)outv)[(size_t)row*128 + t*16 + ln] = (unsigned char)(p & 0xFF);
            } else {
              ((unsigned short*)outv)[(size_t)row*128 + t*16 + ln] = f2bf(v);
            }
          }
        }
      }
    }
  }

  if (POOL){
    __threadfence();
    if (threadIdx.x == 0){
      int old = __hip_atomic_fetch_add(done3, 1, __ATOMIC_ACQ_REL, __HIP_MEMORY_SCOPE_AGENT);
      amLast = (old == (int)gridDim.x - 1);
    }
    __syncthreads();
    if (amLast){
      float* gs = (float*)wt;   // wt dead after tile loop; 34.8KB >= 32KB
      for (int i = threadIdx.x; i < NGRAPH*C_HID; i += 256)
        gs[i] = __hip_atomic_load(&gsum[i], __ATOMIC_RELAXED, __HIP_MEMORY_SCOPE_AGENT);
      __syncthreads();
      for (int idx = threadIdx.x; idx < NGRAPH*COUT; idx += 256){
        int g = idx >> 6, o = idx & 63;
        int rs = clampi(lower_bound_i(batch, M, g), 0, M);
        int re = clampi(lower_bound_i(batch, M, g + 1), rs, M);
        float inv = 1.0f / fmaxf((float)(re - rs), 1.0f);
        float acc2 = 0.f;
        for (int k = 0; k < 128; ++k)
          acc2 += gs[g*C_HID + k] * Wl[k*COUT + o];
        fout[g*COUT + o] = acc2 * inv + bl[o];
      }
    }
  }
}

extern "C" void kernel_launch(void* const* d_in, const int* in_sizes, int n_in,
                              void* d_out, int out_size, void* d_ws, size_t ws_size,
                              hipStream_t stream){
  const float* x0 = (const float*)d_in[0];
  const int* ei   = (const int*)d_in[1];
  const int* batch= (const int*)d_in[2];
  const float* W1 = (const float*)d_in[3];
  const float* b1 = (const float*)d_in[4];
  const float* W2 = (const float*)d_in[5];
  const float* b2 = (const float*)d_in[6];
  const float* W3 = (const float*)d_in[7];
  const float* b3 = (const float*)d_in[8];
  const float* Wl = (const float*)d_in[9];
  const float* bl = (const float*)d_in[10];
  float* out = (float*)d_out;

  int E = in_sizes[1] / 2;
  int N = in_sizes[2];
  const int* src = ei;
  const int* dst = ei + E;
  int NBUK = (N + BKT - 1) / BKT;
  int chunk = (E + NBLK - 1) / NBLK;

  size_t off_acc = 0;
  auto carve = [&](size_t bytes)->size_t{
    size_t r = off_acc; off_acc += (bytes + 255) & ~(size_t)255; return r;
  };
  size_t o_bcnt  = carve((size_t)(NBUK_MAX + 8)*4);         // bcnt + done1 (+pad)
  size_t o_bases = carve((size_t)(NBUK_MAX + 1)*4);
  size_t o_cur   = carve((size_t)NBUK_MAX*4);
  size_t o_offs  = carve((size_t)(N+1)*4);
  size_t o_dinv  = carve((size_t)N*4);
  size_t o_meta  = carve((size_t)E*4);                      // compact CSR src list
  size_t o_rec   = carve((size_t)E*4);                      // bucket-sorted records
  size_t o_yA    = carve((size_t)(N+1)*C_HID);              // fp8 ping (+ zero row N)
  size_t o_yB    = carve((size_t)(N+1)*C_HID);              // fp8 pong (+ zero row N)
  size_t o_aggb  = carve((size_t)N*C_HID*2);                // bf16 agg
  size_t o_wt    = carve((size_t)3*128*128*2);              // bf16 Wt x3
  size_t o_gsum  = carve((size_t)NGRAPH*C_HID*4);           // pooled sums (f32)
  size_t o_done3 = carve(256);
  size_t need = off_acc;

  if (ws_size < need || NBUK > NBUK_MAX){
    k_zero<<<(out_size+255)/256, 256, 0, stream>>>(out, out_size);
    return;
  }

  char* base = (char*)d_ws;
  int* bcnt  = (int*)(base + o_bcnt);
  int* done1 = bcnt + NBUK_MAX;
  int* bases = (int*)(base + o_bases);
  int* cur   = (int*)(base + o_cur);
  int* offs  = (int*)(base + o_offs);
  float* dinv= (float*)(base + o_dinv);
  int* meta  = (int*)(base + o_meta);
  unsigned int* rec   = (unsigned int*)(base + o_rec);
  unsigned short* yA  = (unsigned short*)(base + o_yA);     // fp8 pairs as ushort
  unsigned short* yB  = (unsigned short*)(base + o_yB);
  unsigned int* aggb  = (unsigned int*)(base + o_aggb);
  unsigned short* wt  = (unsigned short*)(base + o_wt);
  float* gsum         = (float*)(base + o_gsum);
  int* done3          = (int*)(base + o_done3);

  hipMemsetAsync(bcnt, 0, (size_t)(NBUK_MAX + 8)*4, stream);
  k_cnt <<<NBLK, 256, 0, stream>>>(dst, bcnt, done1, bases, cur, E, N, NBUK, chunk);
  k_scat<<<NBLK, 256, 0, stream>>>(src, dst, cur, rec, E, N, NBUK, chunk);
  k_csr <<<NBUK, BKT, 0, stream>>>(rec, bases, offs, dinv, meta, E, N, NBUK);

  int xg = (N*64 + 64 + 255)/256;
  k_prepx<<<xg, 256, 0, stream>>>((const float2*)x0, dinv, yA, yB,
                                  W1, W2, W3, wt, gsum, done3, N);

  int spmm_grid = (N + 31) / 32;   // 4 waves/block, 8 nodes per wave

  k_spmm<<<spmm_grid, 256, 0, stream>>>(yA, offs, dinv, meta, aggb, N);
  k_gemm<true , false><<<GEMM_BLOCKS, 256, 0, stream>>>((const unsigned short*)aggb, wt,
      b1, dinv, (void*)yB, nullptr, nullptr, nullptr, nullptr, nullptr, nullptr, N);
  k_spmm<<<spmm_grid, 256, 0, stream>>>(yB, offs, dinv, meta, aggb, N);
  k_gemm<true , false><<<GEMM_BLOCKS, 256, 0, stream>>>((const unsigned short*)aggb, wt + 16384,
      b2, dinv, (void*)yA, nullptr, nullptr, nullptr, nullptr, nullptr, nullptr, N);
  k_spmm<<<spmm_grid, 256, 0, stream>>>(yA, offs, dinv, meta, aggb, N);
  k_gemm<false, true ><<<GEMM_BLOCKS, 256, 0, stream>>>((const unsigned short*)aggb, wt + 2*16384,
      b3, dinv, nullptr, batch, gsum, done3, Wl, bl, out, N);
}

// Round 10
// 343.700 us; speedup vs baseline: 1.4514x; 1.4514x over previous
//
#include <hip/hip_runtime.h>
#include <stdint.h>

#define C_HID 128
#define NGRAPH 64
#define COUT 64
#define NBLK 256      // edge-chunk blocks for cnt/scat
#define BKT 256       // nodes per bucket
#define NBUK_MAX 512
typedef short bf16x8 __attribute__((ext_vector_type(8)));
typedef float f32x4 __attribute__((ext_vector_type(4)));
typedef float f32x2 __attribute__((ext_vector_type(2)));

__device__ __forceinline__ unsigned short f2bf(float f){
  unsigned int u = __builtin_bit_cast(unsigned int, f);
  u = u + 0x7FFFu + ((u >> 16) & 1u);   // RNE
  return (unsigned short)(u >> 16);
}
__device__ __forceinline__ int clampi(int v, int lo, int hi){
  return v < lo ? lo : (v > hi ? hi : v);
}

__global__ void k_zero(float* __restrict__ out, int n){
  int i = blockIdx.x*blockDim.x + threadIdx.x;
  if (i < n) out[i] = 0.f;
}

// ---------- CSR pass 1: bucket totals (LDS hist + 1 global add per (block,bucket));
// last block (done-counter) scans totals in-LDS -> bases[0..NBUK] and cur[] ----------
__global__ __launch_bounds__(256) void k_cnt(const int* __restrict__ dst,
                                             int* __restrict__ bcnt,   // [NBUK_MAX], zeroed
                                             int* __restrict__ done1,  // zeroed
                                             int* __restrict__ bases,  // [NBUK_MAX+1]
                                             int* __restrict__ cur,    // [NBUK_MAX]
                                             int E, int N, int NBUK, int chunk){
  __shared__ int cnt[NBUK_MAX];
  __shared__ int amLast;
  int t = threadIdx.x;
  for (int b = t; b < NBUK; b += 256) cnt[b] = 0;
  __syncthreads();
  int e0 = blockIdx.x*chunk, e1 = min(E, e0 + chunk);
  for (int e = e0 + t; e < e1; e += 256)
    atomicAdd(&cnt[clampi(dst[e], 0, N-1) >> 8], 1);
  __syncthreads();
  for (int b = t; b < NBUK; b += 256)
    if (cnt[b]) atomicAdd(&bcnt[b], cnt[b]);
  __threadfence();
  if (t == 0){
    int old = __hip_atomic_fetch_add(done1, 1, __ATOMIC_ACQ_REL, __HIP_MEMORY_SCOPE_AGENT);
    amLast = (old == (int)gridDim.x - 1);
  }
  __syncthreads();
  if (!amLast) return;

  // last block: exclusive scan of 512 (zero-padded) totals with 256 threads
  __shared__ int sb[512];
  int a0 = __hip_atomic_load(&bcnt[t],       __ATOMIC_RELAXED, __HIP_MEMORY_SCOPE_AGENT);
  int a1 = __hip_atomic_load(&bcnt[t + 256], __ATOMIC_RELAXED, __HIP_MEMORY_SCOPE_AGENT);
  sb[t] = a0; sb[t + 256] = a1;
  __syncthreads();
  for (int off = 1; off < 256; off <<= 1){
    int x0 = (t >= off) ? sb[t - off] : 0;
    int x1 = (t >= off) ? sb[256 + t - off] : 0;
    __syncthreads();
    sb[t] += x0; sb[256 + t] += x1;
    __syncthreads();
  }
  int lowTot = sb[255];
  sb[256 + t] += lowTot;
  __syncthreads();
  bases[t]       = sb[t] - a0;        cur[t]       = sb[t] - a0;
  bases[t + 256] = sb[t + 256] - a1;  cur[t + 256] = sb[t + 256] - a1;
  if (t == 255) bases[512] = sb[511];   // == E; bases sized NBUK_MAX+1
}

// ---------- CSR pass 2: local count -> reserve segment (atomicAdd cur) -> scatter ----
__global__ __launch_bounds__(256) void k_scat(const int* __restrict__ src,
                                              const int* __restrict__ dst,
                                              int* __restrict__ cur,
                                              unsigned int* __restrict__ rec,
                                              int E, int N, int NBUK, int chunk){
  __shared__ int cnt[NBUK_MAX];
  __shared__ int lbase[NBUK_MAX];
  int t = threadIdx.x;
  for (int b = t; b < NBUK; b += 256) cnt[b] = 0;
  __syncthreads();
  int e0 = blockIdx.x*chunk, e1 = min(E, e0 + chunk);
  for (int e = e0 + t; e < e1; e += 256)
    atomicAdd(&cnt[clampi(dst[e], 0, N-1) >> 8], 1);
  __syncthreads();
  for (int b = t; b < NBUK; b += 256)
    lbase[b] = cnt[b] ? atomicAdd(&cur[b], cnt[b]) : 0;
  __syncthreads();
  for (int b = t; b < NBUK; b += 256) cnt[b] = 0;   // reuse as local cursor
  __syncthreads();
  for (int e = e0 + t; e < e1; e += 256){
    int d = clampi(dst[e], 0, N-1);
    int s = clampi(src[e], 0, N-1);
    int b = d >> 8;
    int p = lbase[b] + atomicAdd(&cnt[b], 1);
    rec[p] = (unsigned int)s | ((unsigned int)(d & 255) << 24);
  }
}

// ---------- CSR pass 3: per-bucket local CSR (offs, dinv, meta) ----------
__global__ __launch_bounds__(256) void k_csr(const unsigned int* __restrict__ rec,
                                             const int* __restrict__ bases,
                                             int* __restrict__ offs, float* __restrict__ dinv,
                                             int* __restrict__ meta, int E, int N, int NBUK){
  __shared__ int cnt[BKT], loff[BKT], cur[BKT];
  int b = blockIdx.x, t = threadIdx.x;
  cnt[t] = 0;
  __syncthreads();
  int r0 = bases[b];
  int r1 = bases[b + 1];
  for (int i = r0 + t; i < r1; i += 256)
    atomicAdd(&cnt[rec[i] >> 24], 1);
  __syncthreads();
  loff[t] = cnt[t];
  __syncthreads();
  for (int off = 1; off < BKT; off <<= 1){
    int add = (t >= off) ? loff[t - off] : 0;
    __syncthreads();
    loff[t] += add;
    __syncthreads();
  }
  int excl = loff[t] - cnt[t];
  cur[t] = r0 + excl;
  int node = b*BKT + t;
  if (node < N){
    offs[node] = r0 + excl;
    dinv[node] = rsqrtf((float)(cnt[t] + 1));   // +1 = self loop
  }
  if (b == NBUK-1 && t == 0) offs[N] = E;
  __syncthreads();
  for (int i = r0 + t; i < r1; i += 256){
    unsigned int r = rec[i];
    int p = atomicAdd(&cur[r >> 24], 1);
    meta[p] = (int)(r & 0x00FFFFFFu);
  }
}

// ---------- merged: xcast (y0 = fp8(64*dinv*x0)) + W prep + zero gsum ----------
__global__ void k_prepx(const float2* __restrict__ x, const float* __restrict__ dinv,
                        unsigned short* __restrict__ y, unsigned short* __restrict__ y2,
                        const float* __restrict__ W1, const float* __restrict__ W2,
                        const float* __restrict__ W3, unsigned short* __restrict__ Wt,
                        float* __restrict__ gsum, int N){
  int i = blockIdx.x*256 + threadIdx.x;
  int tot = N*64;
  if (i < tot){
    float2 v = x[i];
    float dn = dinv[i >> 6] * 64.f;
    int p = __builtin_amdgcn_cvt_pk_fp8_f32(v.x*dn, v.y*dn, 0, false);
    y[i] = (unsigned short)(p & 0xFFFF);
  } else if (i < tot + 64){
    y[i] = 0;                       // zero row at index N (gather sink)
    y2[i] = 0;
  }
  if (i < 3*16384){
    int w = i >> 14;
    int r = i & 16383;
    int n = r & 127, k = r >> 7;
    const float* W = (w == 0) ? W1 : (w == 1) ? W2 : W3;
    Wt[(size_t)w*16384 + (size_t)n*128 + k] = f2bf(W[k*128 + n]);
  }
  if (i < NGRAPH*C_HID) gsum[i] = 0.f;
}

// ---------- SpMM v6 (unchanged): 8 nodes/wave, at its L2-duplication service floor ----
__global__ __launch_bounds__(256) void k_spmm(const unsigned short* __restrict__ y,
                       const int* __restrict__ offs,
                       const float* __restrict__ dinv,
                       const int* __restrict__ meta,
                       unsigned int* __restrict__ agg, int N){
  int wv   = __builtin_amdgcn_readfirstlane(threadIdx.x >> 6);
  int lane = threadIdx.x & 63;
  int g = lane >> 3, c = lane & 7;
  int node0 = blockIdx.x*32 + wv*8;
  if (node0 >= N) return;

  int e[9];
  #pragma unroll
  for (int i = 0; i < 9; ++i) e[i] = offs[min(node0 + i, N)];
  int cn[8]; int maxc = 0;
  #pragma unroll
  for (int i = 0; i < 8; ++i){ cn[i] = e[i+1] - e[i]; maxc = max(maxc, cn[i]); }

  int e0l = e[0], cntl = cn[0];
  #pragma unroll
  for (int i = 1; i < 8; ++i){
    e0l  = (g == i) ? e[i]  : e0l;
    cntl = (g == i) ? cn[i] : cntl;
  }
  int nodeg = node0 + g;
  bool nok = nodeg < N;
  int nself = nok ? nodeg : N;              // row N = zero row

  const uint4* yrow = (const uint4*)y;      // row = 8 x 16B

  int mv0 = (c      < cntl) ? meta[e0l + c]      : N;
  int mv1 = (c +  8 < cntl) ? meta[e0l + c +  8] : N;
  int mv2 = (c + 16 < cntl) ? meta[e0l + c + 16] : N;
  int mv3 = (c + 24 < cntl) ? meta[e0l + c + 24] : N;
  uint4 us = yrow[(size_t)nself*8 + c];     // self row
  float dl = dinv[nok ? nodeg : 0];

  f32x2 acc[8];
  { f32x2 f;
    f = __builtin_amdgcn_cvt_pk_f32_fp8((int)us.x, false); acc[0] = f;
    f = __builtin_amdgcn_cvt_pk_f32_fp8((int)us.x, true);  acc[1] = f;
    f = __builtin_amdgcn_cvt_pk_f32_fp8((int)us.y, false); acc[2] = f;
    f = __builtin_amdgcn_cvt_pk_f32_fp8((int)us.y, true);  acc[3] = f;
    f = __builtin_amdgcn_cvt_pk_f32_fp8((int)us.z, false); acc[4] = f;
    f = __builtin_amdgcn_cvt_pk_f32_fp8((int)us.z, true);  acc[5] = f;
    f = __builtin_amdgcn_cvt_pk_f32_fp8((int)us.w, false); acc[6] = f;
    f = __builtin_amdgcn_cvt_pk_f32_fp8((int)us.w, true);  acc[7] = f; }

  uint4 u[8];
#define SWZ(MV, J) __builtin_amdgcn_ds_swizzle(MV, (0x18 | (((J)&7)<<5)))
#define GA(K, SM) u[K] = yrow[(size_t)(unsigned)(SM)*8 + c]
#define CONV8() do{ _Pragma("unroll") \
  for (int k2 = 0; k2 < 8; ++k2){ \
    f32x2 f; \
    f = __builtin_amdgcn_cvt_pk_f32_fp8((int)u[k2].x, false); acc[0] += f; \
    f = __builtin_amdgcn_cvt_pk_f32_fp8((int)u[k2].x, true);  acc[1] += f; \
    f = __builtin_amdgcn_cvt_pk_f32_fp8((int)u[k2].y, false); acc[2] += f; \
    f = __builtin_amdgcn_cvt_pk_f32_fp8((int)u[k2].y, true);  acc[3] += f; \
    f = __builtin_amdgcn_cvt_pk_f32_fp8((int)u[k2].z, false); acc[4] += f; \
    f = __builtin_amdgcn_cvt_pk_f32_fp8((int)u[k2].z, true);  acc[5] += f; \
    f = __builtin_amdgcn_cvt_pk_f32_fp8((int)u[k2].w, false); acc[6] += f; \
    f = __builtin_amdgcn_cvt_pk_f32_fp8((int)u[k2].w, true);  acc[7] += f; } }while(0)

  if (0 < maxc){
    GA(0,SWZ(mv0,0)); GA(1,SWZ(mv0,1)); GA(2,SWZ(mv0,2)); GA(3,SWZ(mv0,3));
    GA(4,SWZ(mv0,4)); GA(5,SWZ(mv0,5)); GA(6,SWZ(mv0,6)); GA(7,SWZ(mv0,7));
    __builtin_amdgcn_sched_barrier(0);
    CONV8();
  }
  if (8 < maxc){
    GA(0,SWZ(mv1,0)); GA(1,SWZ(mv1,1)); GA(2,SWZ(mv1,2)); GA(3,SWZ(mv1,3));
    GA(4,SWZ(mv1,4)); GA(5,SWZ(mv1,5)); GA(6,SWZ(mv1,6)); GA(7,SWZ(mv1,7));
    __builtin_amdgcn_sched_barrier(0);
    CONV8();
  }
  if (16 < maxc){
    GA(0,SWZ(mv2,0)); GA(1,SWZ(mv2,1)); GA(2,SWZ(mv2,2)); GA(3,SWZ(mv2,3));
    GA(4,SWZ(mv2,4)); GA(5,SWZ(mv2,5)); GA(6,SWZ(mv2,6)); GA(7,SWZ(mv2,7));
    __builtin_amdgcn_sched_barrier(0);
    CONV8();
  }
  if (24 < maxc){
    GA(0,SWZ(mv3,0)); GA(1,SWZ(mv3,1)); GA(2,SWZ(mv3,2)); GA(3,SWZ(mv3,3));
    GA(4,SWZ(mv3,4)); GA(5,SWZ(mv3,5)); GA(6,SWZ(mv3,6)); GA(7,SWZ(mv3,7));
    __builtin_amdgcn_sched_barrier(0);
    CONV8();
  }
#undef SWZ
#undef GA
#undef CONV8

  for (int j = 32; j < maxc; ++j){
    int sm = (j < cntl) ? meta[e0l + j] : N;
    uint4 t = yrow[(size_t)(unsigned)sm*8 + c];
    f32x2 f;
    f = __builtin_amdgcn_cvt_pk_f32_fp8((int)t.x, false); acc[0] += f;
    f = __builtin_amdgcn_cvt_pk_f32_fp8((int)t.x, true);  acc[1] += f;
    f = __builtin_amdgcn_cvt_pk_f32_fp8((int)t.y, false); acc[2] += f;
    f = __builtin_amdgcn_cvt_pk_f32_fp8((int)t.y, true);  acc[3] += f;
    f = __builtin_amdgcn_cvt_pk_f32_fp8((int)t.z, false); acc[4] += f;
    f = __builtin_amdgcn_cvt_pk_f32_fp8((int)t.z, true);  acc[5] += f;
    f = __builtin_amdgcn_cvt_pk_f32_fp8((int)t.w, false); acc[6] += f;
    f = __builtin_amdgcn_cvt_pk_f32_fp8((int)t.w, true);  acc[7] += f;
  }

  float dn = dl * 0.015625f;   // /64
  if (nok){
    uint4 w0, w1;
    w0.x = (unsigned int)f2bf(acc[0].x*dn) | ((unsigned int)f2bf(acc[0].y*dn) << 16);
    w0.y = (unsigned int)f2bf(acc[1].x*dn) | ((unsigned int)f2bf(acc[1].y*dn) << 16);
    w0.z = (unsigned int)f2bf(acc[2].x*dn) | ((unsigned int)f2bf(acc[2].y*dn) << 16);
    w0.w = (unsigned int)f2bf(acc[3].x*dn) | ((unsigned int)f2bf(acc[3].y*dn) << 16);
    w1.x = (unsigned int)f2bf(acc[4].x*dn) | ((unsigned int)f2bf(acc[4].y*dn) << 16);
    w1.y = (unsigned int)f2bf(acc[5].x*dn) | ((unsigned int)f2bf(acc[5].y*dn) << 16);
    w1.z = (unsigned int)f2bf(acc[6].x*dn) | ((unsigned int)f2bf(acc[6].y*dn) << 16);
    w1.w = (unsigned int)f2bf(acc[7].x*dn) | ((unsigned int)f2bf(acc[7].y*dn) << 16);
    *(uint4*)(agg + (size_t)nodeg*64 + c*8)     = w0;
    *(uint4*)(agg + (size_t)nodeg*64 + c*8 + 4) = w1;
  }
}

// ---------- GEMM (v7 version): h = relu(A@W + b); FP8OUT -> fp8 y'; POOL -> gsum ------
// v8 post-mortem: folding k_fin into the POOL gemm's last block serialized
// ~32 dependent-load binary searches onto ONE CU (240us at 5% occupancy).
// k_fin stays a separate 64-block dispatch (~2-3us total).
#define GEMM_BLOCKS 512
template<bool FP8OUT, bool POOL>
__global__ __launch_bounds__(256) void k_gemm(const unsigned short* __restrict__ A,
                                              const unsigned short* __restrict__ Wt,
                                              const float* __restrict__ bias,
                                              const float* __restrict__ scale,
                                              void* __restrict__ outv,
                                              const int* __restrict__ batch,
                                              float* __restrict__ gsum, int M){
  __shared__ unsigned short wt[128*136];
  __shared__ float gbuf[2][C_HID];
  {
    const uint4* wsrc = (const uint4*)Wt;     // 4096 uint4 (8 shorts each)
    for (int i = threadIdx.x; i < 4096; i += 256){
      uint4 v = wsrc[i];
      int n = i >> 4, kblk = i & 15;          // row = 16 uint4
      *(uint4*)&wt[n*136 + kblk*8] = v;
    }
  }
  __syncthreads();

  int wv = threadIdx.x >> 6, lane = threadIdx.x & 63;
  int q = lane >> 4, ln = lane & 15;
  int tiles = (M + 63) >> 6;

  for (int tile = blockIdx.x; tile < tiles; tile += GEMM_BLOCKS){
    int m0 = tile*64 + wv*16;
    int arow = m0 + ln;
    bool arow_ok = (arow < M);
    int arow_s = arow_ok ? arow : 0;

    f32x4 zero = {0.f, 0.f, 0.f, 0.f};
    f32x4 acc[8];
    #pragma unroll
    for (int t = 0; t < 8; ++t) acc[t] = zero;

    #pragma unroll
    for (int kk = 0; kk < 4; ++kk){
      bf16x8 a;
      if (arow_ok){
        __builtin_memcpy(&a, A + (size_t)arow_s*128 + kk*32 + q*8, 16);
      } else {
        a = (bf16x8){0,0,0,0,0,0,0,0};
      }
      #pragma unroll
      for (int t = 0; t < 8; ++t){
        bf16x8 b;
        __builtin_memcpy(&b, &wt[(t*16 + ln)*136 + kk*32 + q*8], 16);
        acc[t] = __builtin_amdgcn_mfma_f32_16x16x32_bf16(a, b, acc[t], 0, 0, 0);
      }
    }

    if (POOL){
      int tb = tile*64;
      int gA = batch[tb];
      int gB = batch[min(tb + 63, M - 1)];
      bool multi = (gB > gA + 1);             // defensive; ~impossible
      __syncthreads();                        // prior tile's gbuf flush done
      ((float*)gbuf)[threadIdx.x] = 0.f;      // 256 slots = 2 x 128
      __syncthreads();
      #pragma unroll
      for (int t = 0; t < 8; ++t){
        float bv = bias[t*16 + ln];
        int ch = t*16 + ln;
        float s0 = 0.f, s1 = 0.f;
        #pragma unroll
        for (int r = 0; r < 4; ++r){
          int row = m0 + q*4 + r;
          if (row < M){
            float v = acc[t][r] + bv;
            v = v > 0.f ? v : 0.f;
            if (multi){
              atomicAdd(&gsum[(size_t)batch[row]*C_HID + ch], v);
            } else if (gB > gA && batch[row] != gA){
              s1 += v;
            } else {
              s0 += v;
            }
          }
        }
        if (!multi){
          if (s0 != 0.f) atomicAdd(&gbuf[0][ch], s0);
          if (s1 != 0.f) atomicAdd(&gbuf[1][ch], s1);
        }
      }
      __syncthreads();
      if (!multi){
        int sel = threadIdx.x >> 7, ch2 = threadIdx.x & 127;
        if (sel == 0 || gB > gA){
          float v = ((float*)gbuf)[threadIdx.x];
          if (v != 0.f)
            atomicAdd(&gsum[(size_t)((sel == 0) ? gA : gB)*C_HID + ch2], v);
        }
      }
    } else {
      float sc[4];
      #pragma unroll
      for (int r = 0; r < 4; ++r){
        int row = m0 + q*4 + r;
        sc[r] = (FP8OUT && row < M) ? scale[row] * 64.f : 1.0f;
      }
      #pragma unroll
      for (int t = 0; t < 8; ++t){
        float bv = bias[t*16 + ln];
        #pragma unroll
        for (int r = 0; r < 4; ++r){
          int row = m0 + q*4 + r;
          if (row < M){
            float v = acc[t][r] + bv;
            v = v > 0.f ? v : 0.f;
            if (FP8OUT){
              v *= sc[r];
              int p = __builtin_amdgcn_cvt_pk_fp8_f32(v, v, 0, false);
              ((unsigned char*)outv)[(size_t)row*128 + t*16 + ln] = (unsigned char)(p & 0xFF);
            } else {
              ((unsigned short*)outv)[(size_t)row*128 + t*16 + ln] = f2bf(v);
            }
          }
        }
      }
    }
  }
}

// ---------- final: out[g] = (gsum[g]/cnt_g) @ Wlin + blin (64 parallel blocks) --------
__device__ __forceinline__ int lower_bound_i(const int* arr, int n, int val){
  int lo = 0, hi = n;
  while (lo < hi){ int mid = (lo + hi) >> 1; if (arr[mid] < val) lo = mid + 1; else hi = mid; }
  return lo;
}

__global__ void k_fin(const float* __restrict__ gsum, const int* __restrict__ batch,
                      const float* __restrict__ Wl, const float* __restrict__ bl,
                      float* __restrict__ out, int N){
  __shared__ float srow[C_HID];
  int g = blockIdx.x, t = threadIdx.x;      // 128 threads
  srow[t] = gsum[(size_t)g*C_HID + t];
  __syncthreads();
  if (t < COUT){
    int rs = clampi(lower_bound_i(batch, N, g), 0, N);
    int re = clampi(lower_bound_i(batch, N, g + 1), rs, N);
    float inv = 1.0f / fmaxf((float)(re - rs), 1.0f);
    float o = 0.f;
    for (int k = 0; k < 128; ++k)
      o += srow[k] * Wl[k*COUT + t];
    out[g*COUT + t] = o * inv + bl[t];
  }
}

extern "C" void kernel_launch(void* const* d_in, const int* in_sizes, int n_in,
                              void* d_out, int out_size, void* d_ws, size_t ws_size,
                              hipStream_t stream){
  const float* x0 = (const float*)d_in[0];
  const int* ei   = (const int*)d_in[1];
  const int* batch= (const int*)d_in[2];
  const float* W1 = (const float*)d_in[3];
  const float* b1 = (const float*)d_in[4];
  const float* W2 = (const float*)d_in[5];
  const float* b2 = (const float*)d_in[6];
  const float* W3 = (const float*)d_in[7];
  const float* b3 = (const float*)d_in[8];
  const float* Wl = (const float*)d_in[9];
  const float* bl = (const float*)d_in[10];
  float* out = (float*)d_out;

  int E = in_sizes[1] / 2;
  int N = in_sizes[2];
  const int* src = ei;
  const int* dst = ei + E;
  int NBUK = (N + BKT - 1) / BKT;
  int chunk = (E + NBLK - 1) / NBLK;

  size_t off_acc = 0;
  auto carve = [&](size_t bytes)->size_t{
    size_t r = off_acc; off_acc += (bytes + 255) & ~(size_t)255; return r;
  };
  size_t o_bcnt  = carve((size_t)(NBUK_MAX + 8)*4);         // bcnt + done1 (+pad)
  size_t o_bases = carve((size_t)(NBUK_MAX + 1)*4);
  size_t o_cur   = carve((size_t)NBUK_MAX*4);
  size_t o_offs  = carve((size_t)(N+1)*4);
  size_t o_dinv  = carve((size_t)N*4);
  size_t o_meta  = carve((size_t)E*4);                      // compact CSR src list
  size_t o_rec   = carve((size_t)E*4);                      // bucket-sorted records
  size_t o_yA    = carve((size_t)(N+1)*C_HID);              // fp8 ping (+ zero row N)
  size_t o_yB    = carve((size_t)(N+1)*C_HID);              // fp8 pong (+ zero row N)
  size_t o_aggb  = carve((size_t)N*C_HID*2);                // bf16 agg
  size_t o_wt    = carve((size_t)3*128*128*2);              // bf16 Wt x3
  size_t o_gsum  = carve((size_t)NGRAPH*C_HID*4);           // pooled sums (f32)
  size_t need = off_acc;

  if (ws_size < need || NBUK > NBUK_MAX){
    k_zero<<<(out_size+255)/256, 256, 0, stream>>>(out, out_size);
    return;
  }

  char* base = (char*)d_ws;
  int* bcnt  = (int*)(base + o_bcnt);
  int* done1 = bcnt + NBUK_MAX;
  int* bases = (int*)(base + o_bases);
  int* cur   = (int*)(base + o_cur);
  int* offs  = (int*)(base + o_offs);
  float* dinv= (float*)(base + o_dinv);
  int* meta  = (int*)(base + o_meta);
  unsigned int* rec   = (unsigned int*)(base + o_rec);
  unsigned short* yA  = (unsigned short*)(base + o_yA);     // fp8 pairs as ushort
  unsigned short* yB  = (unsigned short*)(base + o_yB);
  unsigned int* aggb  = (unsigned int*)(base + o_aggb);
  unsigned short* wt  = (unsigned short*)(base + o_wt);
  float* gsum         = (float*)(base + o_gsum);

  hipMemsetAsync(bcnt, 0, (size_t)(NBUK_MAX + 8)*4, stream);
  k_cnt <<<NBLK, 256, 0, stream>>>(dst, bcnt, done1, bases, cur, E, N, NBUK, chunk);
  k_scat<<<NBLK, 256, 0, stream>>>(src, dst, cur, rec, E, N, NBUK, chunk);
  k_csr <<<NBUK, BKT, 0, stream>>>(rec, bases, offs, dinv, meta, E, N, NBUK);

  int xg = (N*64 + 64 + 255)/256;
  k_prepx<<<xg, 256, 0, stream>>>((const float2*)x0, dinv, yA, yB,
                                  W1, W2, W3, wt, gsum, N);

  int spmm_grid = (N + 31) / 32;   // 4 waves/block, 8 nodes per wave

  k_spmm<<<spmm_grid, 256, 0, stream>>>(yA, offs, dinv, meta, aggb, N);
  k_gemm<true , false><<<GEMM_BLOCKS, 256, 0, stream>>>((const unsigned short*)aggb, wt,
      b1, dinv, (void*)yB, nullptr, nullptr, N);
  k_spmm<<<spmm_grid, 256, 0, stream>>>(yB, offs, dinv, meta, aggb, N);
  k_gemm<true , false><<<GEMM_BLOCKS, 256, 0, stream>>>((const unsigned short*)aggb, wt + 16384,
      b2, dinv, (void*)yA, nullptr, nullptr, N);
  k_spmm<<<spmm_grid, 256, 0, stream>>>(yA, offs, dinv, meta, aggb, N);
  k_gemm<false, true ><<<GEMM_BLOCKS, 256, 0, stream>>>((const unsigned short*)aggb, wt + 2*16384,
      b3, dinv, nullptr, batch, gsum, N);

  k_fin<<<NGRAPH, 128, 0, stream>>>(gsum, batch, Wl, bl, out, N);
}

// Round 11
// 327.706 us; speedup vs baseline: 1.5223x; 1.0488x over previous
//
#include <hip/hip_runtime.h>
#include <stdint.h>

#define C_HID 128
#define NGRAPH 64
#define COUT 64
#define NBLK 256      // edge-chunk blocks for cnt/scat
#define BKT 256       // nodes per bucket
#define NBUK_MAX 512
#define SCAN_CH 4096  // scan elements per block (256 thr x 16)

typedef short bf16x8 __attribute__((ext_vector_type(8)));
typedef float f32x4 __attribute__((ext_vector_type(4)));
typedef float f32x2 __attribute__((ext_vector_type(2)));

__device__ __forceinline__ unsigned short f2bf(float f){
  unsigned int u = __builtin_bit_cast(unsigned int, f);
  u = u + 0x7FFFu + ((u >> 16) & 1u);   // RNE
  return (unsigned short)(u >> 16);
}
__device__ __forceinline__ int clampi(int v, int lo, int hi){
  return v < lo ? lo : (v > hi ? hi : v);
}

__global__ void k_zero(float* __restrict__ out, int n){
  int i = blockIdx.x*blockDim.x + threadIdx.x;
  if (i < n) out[i] = 0.f;
}

// ---------- CSR build, pass 1: per-(block,bucket) histogram ----------
// v9 post-mortem: the "consolidated" 3-dispatch CSR (global-atomic totals +
// done-counter scan + double-histogram scat) was +10us vs this scan chain —
// dispatch-count reduction loses when it serializes work. Restored verbatim.
__global__ __launch_bounds__(256) void k_cnt(const int* __restrict__ dst,
                                             int* __restrict__ cntg,
                                             int E, int N, int NBUK, int chunk){
  __shared__ int cnt[NBUK_MAX];
  int blk = blockIdx.x, t = threadIdx.x;
  for (int b = t; b < NBUK; b += 256) cnt[b] = 0;
  __syncthreads();
  int e0 = blk*chunk, e1 = min(E, e0 + chunk);
  for (int e = e0 + t; e < e1; e += 256)
    atomicAdd(&cnt[clampi(dst[e], 0, N-1) >> 8], 1);
  __syncthreads();
  for (int b = t; b < NBUK; b += 256)
    cntg[b*NBLK + blk] = cnt[b];          // bucket-major layout for the scan
}

// ---------- pass 2: hierarchical exclusive scan of n counts ----------
__global__ __launch_bounds__(256) void k_scanA(const int* __restrict__ cnt,
                                               int* __restrict__ bsum, int n){
  __shared__ int red[256];
  int blk = blockIdx.x, t = threadIdx.x;
  int base = blk*SCAN_CH + t*16;
  int s = 0;
  #pragma unroll
  for (int j = 0; j < 16; ++j){ int i = base + j; s += (i < n) ? cnt[i] : 0; }
  red[t] = s; __syncthreads();
  for (int off = 128; off > 0; off >>= 1){
    if (t < off) red[t] += red[t + off];
    __syncthreads();
  }
  if (t == 0) bsum[blk] = red[0];
}

// single block; nb <= 256
__global__ __launch_bounds__(256) void k_scanB(const int* __restrict__ bsum,
                                               int* __restrict__ bbase,
                                               int* __restrict__ bases, int nb, int n){
  __shared__ int buf[256];
  int t = threadIdx.x;
  int v = (t < nb) ? bsum[t] : 0;
  buf[t] = v; __syncthreads();
  for (int off = 1; off < 256; off <<= 1){
    int add = (t >= off) ? buf[t-off] : 0;
    __syncthreads();
    buf[t] += add;
    __syncthreads();
  }
  if (t < nb) bbase[t] = buf[t] - v;       // exclusive
  if (t == nb-1) bases[n] = buf[t];        // total == E
}

__global__ __launch_bounds__(256) void k_scanC(const int* __restrict__ cnt,
                                               const int* __restrict__ bbase,
                                               int* __restrict__ bases, int n){
  __shared__ int buf[256];
  int blk = blockIdx.x, t = threadIdx.x;
  int base = blk*SCAN_CH + t*16;
  int loc[16]; int s = 0;
  #pragma unroll
  for (int j = 0; j < 16; ++j){ int i = base + j; loc[j] = (i < n) ? cnt[i] : 0; s += loc[j]; }
  buf[t] = s; __syncthreads();
  for (int off = 1; off < 256; off <<= 1){
    int add = (t >= off) ? buf[t-off] : 0;
    __syncthreads();
    buf[t] += add;
    __syncthreads();
  }
  int run = bbase[blk] + buf[t] - s;       // exclusive prefix for this thread
  #pragma unroll
  for (int j = 0; j < 16; ++j){
    int i = base + j;
    if (i < n) bases[i] = run;
    run += loc[j];
  }
}

// ---------- pass 3: scatter packed records into per-(block,bucket) segments ----------
__global__ __launch_bounds__(256) void k_scat(const int* __restrict__ src,
                                              const int* __restrict__ dst,
                                              const int* __restrict__ bases,
                                              unsigned int* __restrict__ rec,
                                              int E, int N, int NBUK, int chunk){
  __shared__ int cur[NBUK_MAX];
  int blk = blockIdx.x, t = threadIdx.x;
  for (int b = t; b < NBUK; b += 256) cur[b] = bases[b*NBLK + blk];
  __syncthreads();
  int e0 = blk*chunk, e1 = min(E, e0 + chunk);
  for (int e = e0 + t; e < e1; e += 256){
    int d = clampi(dst[e], 0, N-1);
    int s = clampi(src[e], 0, N-1);
    int p = atomicAdd(&cur[d >> 8], 1);    // LDS atomic
    rec[p] = (unsigned int)s | ((unsigned int)(d & 255) << 24);
  }
}

// ---------- pass 4: per-bucket local CSR (offs, dinv, meta) ----------
__global__ __launch_bounds__(256) void k_csr(const unsigned int* __restrict__ rec,
                                             const int* __restrict__ bases,
                                             int* __restrict__ offs, float* __restrict__ dinv,
                                             int* __restrict__ meta, int E, int N, int NBUK){
  __shared__ int cnt[BKT], loff[BKT], cur[BKT];
  int b = blockIdx.x, t = threadIdx.x;
  cnt[t] = 0;
  __syncthreads();
  int r0 = bases[b*NBLK];
  int r1 = (b+1 < NBUK) ? bases[(b+1)*NBLK] : E;
  for (int i = r0 + t; i < r1; i += 256)
    atomicAdd(&cnt[rec[i] >> 24], 1);
  __syncthreads();
  loff[t] = cnt[t];
  __syncthreads();
  for (int off = 1; off < BKT; off <<= 1){
    int add = (t >= off) ? loff[t - off] : 0;
    __syncthreads();
    loff[t] += add;
    __syncthreads();
  }
  int excl = loff[t] - cnt[t];
  cur[t] = r0 + excl;
  int node = b*BKT + t;
  if (node < N){
    offs[node] = r0 + excl;
    dinv[node] = rsqrtf((float)(cnt[t] + 1));   // +1 = self loop
  }
  if (b == NBUK-1 && t == 0) offs[N] = E;
  __syncthreads();
  for (int i = r0 + t; i < r1; i += 256){
    unsigned int r = rec[i];
    int p = atomicAdd(&cur[r >> 24], 1);
    meta[p] = (int)(r & 0x00FFFFFFu);
  }
}

// ---------- merged: xcast (y0 = fp8(64*dinv*x0)) + W prep + zero gsum ----------
// S=64 (exact pow2) keeps y values in e4m3's normal range (~0.1..80).
__global__ void k_prepx(const float2* __restrict__ x, const float* __restrict__ dinv,
                        unsigned short* __restrict__ y, unsigned short* __restrict__ y2,
                        const float* __restrict__ W1, const float* __restrict__ W2,
                        const float* __restrict__ W3, unsigned short* __restrict__ Wt,
                        float* __restrict__ gsum, int N){
  int i = blockIdx.x*256 + threadIdx.x;
  int tot = N*64;
  if (i < tot){
    float2 v = x[i];
    float dn = dinv[i >> 6] * 64.f;
    int p = __builtin_amdgcn_cvt_pk_fp8_f32(v.x*dn, v.y*dn, 0, false);
    y[i] = (unsigned short)(p & 0xFFFF);
  } else if (i < tot + 64){
    y[i] = 0;                       // zero row at index N (gather sink)
    y2[i] = 0;
  }
  if (i < 3*16384){
    int w = i >> 14;
    int r = i & 16383;
    int n = r & 127, k = r >> 7;
    const float* W = (w == 0) ? W1 : (w == 1) ? W2 : W3;
    Wt[(size_t)w*16384 + (size_t)n*128 + k] = f2bf(W[k*128 + n]);
  }
  if (i < NGRAPH*C_HID) gsum[i] = 0.f;
}

// ---------- SpMM v6 (unchanged): 8 nodes/wave, at its L2-duplication service floor ----
__global__ __launch_bounds__(256) void k_spmm(const unsigned short* __restrict__ y,
                       const int* __restrict__ offs,
                       const float* __restrict__ dinv,
                       const int* __restrict__ meta,
                       unsigned int* __restrict__ agg, int N){
  int wv   = __builtin_amdgcn_readfirstlane(threadIdx.x >> 6);
  int lane = threadIdx.x & 63;
  int g = lane >> 3, c = lane & 7;
  int node0 = blockIdx.x*32 + wv*8;
  if (node0 >= N) return;

  int e[9];
  #pragma unroll
  for (int i = 0; i < 9; ++i) e[i] = offs[min(node0 + i, N)];
  int cn[8]; int maxc = 0;
  #pragma unroll
  for (int i = 0; i < 8; ++i){ cn[i] = e[i+1] - e[i]; maxc = max(maxc, cn[i]); }

  int e0l = e[0], cntl = cn[0];
  #pragma unroll
  for (int i = 1; i < 8; ++i){
    e0l  = (g == i) ? e[i]  : e0l;
    cntl = (g == i) ? cn[i] : cntl;
  }
  int nodeg = node0 + g;
  bool nok = nodeg < N;
  int nself = nok ? nodeg : N;              // row N = zero row

  const uint4* yrow = (const uint4*)y;      // row = 8 x 16B

  int mv0 = (c      < cntl) ? meta[e0l + c]      : N;
  int mv1 = (c +  8 < cntl) ? meta[e0l + c +  8] : N;
  int mv2 = (c + 16 < cntl) ? meta[e0l + c + 16] : N;
  int mv3 = (c + 24 < cntl) ? meta[e0l + c + 24] : N;
  uint4 us = yrow[(size_t)nself*8 + c];     // self row
  float dl = dinv[nok ? nodeg : 0];

  f32x2 acc[8];
  { f32x2 f;
    f = __builtin_amdgcn_cvt_pk_f32_fp8((int)us.x, false); acc[0] = f;
    f = __builtin_amdgcn_cvt_pk_f32_fp8((int)us.x, true);  acc[1] = f;
    f = __builtin_amdgcn_cvt_pk_f32_fp8((int)us.y, false); acc[2] = f;
    f = __builtin_amdgcn_cvt_pk_f32_fp8((int)us.y, true);  acc[3] = f;
    f = __builtin_amdgcn_cvt_pk_f32_fp8((int)us.z, false); acc[4] = f;
    f = __builtin_amdgcn_cvt_pk_f32_fp8((int)us.z, true);  acc[5] = f;
    f = __builtin_amdgcn_cvt_pk_f32_fp8((int)us.w, false); acc[6] = f;
    f = __builtin_amdgcn_cvt_pk_f32_fp8((int)us.w, true);  acc[7] = f; }

  uint4 u[8];
#define SWZ(MV, J) __builtin_amdgcn_ds_swizzle(MV, (0x18 | (((J)&7)<<5)))
#define GA(K, SM) u[K] = yrow[(size_t)(unsigned)(SM)*8 + c]
#define CONV8() do{ _Pragma("unroll") \
  for (int k2 = 0; k2 < 8; ++k2){ \
    f32x2 f; \
    f = __builtin_amdgcn_cvt_pk_f32_fp8((int)u[k2].x, false); acc[0] += f; \
    f = __builtin_amdgcn_cvt_pk_f32_fp8((int)u[k2].x, true);  acc[1] += f; \
    f = __builtin_amdgcn_cvt_pk_f32_fp8((int)u[k2].y, false); acc[2] += f; \
    f = __builtin_amdgcn_cvt_pk_f32_fp8((int)u[k2].y, true);  acc[3] += f; \
    f = __builtin_amdgcn_cvt_pk_f32_fp8((int)u[k2].z, false); acc[4] += f; \
    f = __builtin_amdgcn_cvt_pk_f32_fp8((int)u[k2].z, true);  acc[5] += f; \
    f = __builtin_amdgcn_cvt_pk_f32_fp8((int)u[k2].w, false); acc[6] += f; \
    f = __builtin_amdgcn_cvt_pk_f32_fp8((int)u[k2].w, true);  acc[7] += f; } }while(0)

  if (0 < maxc){
    GA(0,SWZ(mv0,0)); GA(1,SWZ(mv0,1)); GA(2,SWZ(mv0,2)); GA(3,SWZ(mv0,3));
    GA(4,SWZ(mv0,4)); GA(5,SWZ(mv0,5)); GA(6,SWZ(mv0,6)); GA(7,SWZ(mv0,7));
    __builtin_amdgcn_sched_barrier(0);
    CONV8();
  }
  if (8 < maxc){
    GA(0,SWZ(mv1,0)); GA(1,SWZ(mv1,1)); GA(2,SWZ(mv1,2)); GA(3,SWZ(mv1,3));
    GA(4,SWZ(mv1,4)); GA(5,SWZ(mv1,5)); GA(6,SWZ(mv1,6)); GA(7,SWZ(mv1,7));
    __builtin_amdgcn_sched_barrier(0);
    CONV8();
  }
  if (16 < maxc){
    GA(0,SWZ(mv2,0)); GA(1,SWZ(mv2,1)); GA(2,SWZ(mv2,2)); GA(3,SWZ(mv2,3));
    GA(4,SWZ(mv2,4)); GA(5,SWZ(mv2,5)); GA(6,SWZ(mv2,6)); GA(7,SWZ(mv2,7));
    __builtin_amdgcn_sched_barrier(0);
    CONV8();
  }
  if (24 < maxc){
    GA(0,SWZ(mv3,0)); GA(1,SWZ(mv3,1)); GA(2,SWZ(mv3,2)); GA(3,SWZ(mv3,3));
    GA(4,SWZ(mv3,4)); GA(5,SWZ(mv3,5)); GA(6,SWZ(mv3,6)); GA(7,SWZ(mv3,7));
    __builtin_amdgcn_sched_barrier(0);
    CONV8();
  }
#undef SWZ
#undef GA
#undef CONV8

  for (int j = 32; j < maxc; ++j){
    int sm = (j < cntl) ? meta[e0l + j] : N;
    uint4 t = yrow[(size_t)(unsigned)sm*8 + c];
    f32x2 f;
    f = __builtin_amdgcn_cvt_pk_f32_fp8((int)t.x, false); acc[0] += f;
    f = __builtin_amdgcn_cvt_pk_f32_fp8((int)t.x, true);  acc[1] += f;
    f = __builtin_amdgcn_cvt_pk_f32_fp8((int)t.y, false); acc[2] += f;
    f = __builtin_amdgcn_cvt_pk_f32_fp8((int)t.y, true);  acc[3] += f;
    f = __builtin_amdgcn_cvt_pk_f32_fp8((int)t.z, false); acc[4] += f;
    f = __builtin_amdgcn_cvt_pk_f32_fp8((int)t.z, true);  acc[5] += f;
    f = __builtin_amdgcn_cvt_pk_f32_fp8((int)t.w, false); acc[6] += f;
    f = __builtin_amdgcn_cvt_pk_f32_fp8((int)t.w, true);  acc[7] += f;
  }

  float dn = dl * 0.015625f;   // /64
  if (nok){
    uint4 w0, w1;
    w0.x = (unsigned int)f2bf(acc[0].x*dn) | ((unsigned int)f2bf(acc[0].y*dn) << 16);
    w0.y = (unsigned int)f2bf(acc[1].x*dn) | ((unsigned int)f2bf(acc[1].y*dn) << 16);
    w0.z = (unsigned int)f2bf(acc[2].x*dn) | ((unsigned int)f2bf(acc[2].y*dn) << 16);
    w0.w = (unsigned int)f2bf(acc[3].x*dn) | ((unsigned int)f2bf(acc[3].y*dn) << 16);
    w1.x = (unsigned int)f2bf(acc[4].x*dn) | ((unsigned int)f2bf(acc[4].y*dn) << 16);
    w1.y = (unsigned int)f2bf(acc[5].x*dn) | ((unsigned int)f2bf(acc[5].y*dn) << 16);
    w1.z = (unsigned int)f2bf(acc[6].x*dn) | ((unsigned int)f2bf(acc[6].y*dn) << 16);
    w1.w = (unsigned int)f2bf(acc[7].x*dn) | ((unsigned int)f2bf(acc[7].y*dn) << 16);
    *(uint4*)(agg + (size_t)nodeg*64 + c*8)     = w0;
    *(uint4*)(agg + (size_t)nodeg*64 + c*8 + 4) = w1;
  }
}

// ---------- GEMM (v7 version): h = relu(A@W + b); FP8OUT -> fp8 y'; POOL -> gsum ------
#define GEMM_BLOCKS 512
template<bool FP8OUT, bool POOL>
__global__ __launch_bounds__(256) void k_gemm(const unsigned short* __restrict__ A,
                                              const unsigned short* __restrict__ Wt,
                                              const float* __restrict__ bias,
                                              const float* __restrict__ scale,
                                              void* __restrict__ outv,
                                              const int* __restrict__ batch,
                                              float* __restrict__ gsum, int M){
  __shared__ unsigned short wt[128*136];
  __shared__ float gbuf[2][C_HID];
  {
    const uint4* wsrc = (const uint4*)Wt;     // 4096 uint4 (8 shorts each)
    for (int i = threadIdx.x; i < 4096; i += 256){
      uint4 v = wsrc[i];
      int n = i >> 4, kblk = i & 15;          // row = 16 uint4
      *(uint4*)&wt[n*136 + kblk*8] = v;
    }
  }
  __syncthreads();

  int wv = threadIdx.x >> 6, lane = threadIdx.x & 63;
  int q = lane >> 4, ln = lane & 15;
  int tiles = (M + 63) >> 6;

  for (int tile = blockIdx.x; tile < tiles; tile += GEMM_BLOCKS){
    int m0 = tile*64 + wv*16;
    int arow = m0 + ln;
    bool arow_ok = (arow < M);
    int arow_s = arow_ok ? arow : 0;

    f32x4 zero = {0.f, 0.f, 0.f, 0.f};
    f32x4 acc[8];
    #pragma unroll
    for (int t = 0; t < 8; ++t) acc[t] = zero;

    #pragma unroll
    for (int kk = 0; kk < 4; ++kk){
      bf16x8 a;
      if (arow_ok){
        __builtin_memcpy(&a, A + (size_t)arow_s*128 + kk*32 + q*8, 16);
      } else {
        a = (bf16x8){0,0,0,0,0,0,0,0};
      }
      #pragma unroll
      for (int t = 0; t < 8; ++t){
        bf16x8 b;
        __builtin_memcpy(&b, &wt[(t*16 + ln)*136 + kk*32 + q*8], 16);
        acc[t] = __builtin_amdgcn_mfma_f32_16x16x32_bf16(a, b, acc[t], 0, 0, 0);
      }
    }

    if (POOL){
      int tb = tile*64;
      int gA = batch[tb];
      int gB = batch[min(tb + 63, M - 1)];
      bool multi = (gB > gA + 1);             // defensive; ~impossible
      __syncthreads();                        // prior tile's gbuf flush done
      ((float*)gbuf)[threadIdx.x] = 0.f;      // 256 slots = 2 x 128
      __syncthreads();
      #pragma unroll
      for (int t = 0; t < 8; ++t){
        float bv = bias[t*16 + ln];
        int ch = t*16 + ln;
        float s0 = 0.f, s1 = 0.f;
        #pragma unroll
        for (int r = 0; r < 4; ++r){
          int row = m0 + q*4 + r;
          if (row < M){
            float v = acc[t][r] + bv;
            v = v > 0.f ? v : 0.f;
            if (multi){
              atomicAdd(&gsum[(size_t)batch[row]*C_HID + ch], v);
            } else if (gB > gA && batch[row] != gA){
              s1 += v;
            } else {
              s0 += v;
            }
          }
        }
        if (!multi){
          if (s0 != 0.f) atomicAdd(&gbuf[0][ch], s0);
          if (s1 != 0.f) atomicAdd(&gbuf[1][ch], s1);
        }
      }
      __syncthreads();
      if (!multi){
        int sel = threadIdx.x >> 7, ch2 = threadIdx.x & 127;
        if (sel == 0 || gB > gA){
          float v = ((float*)gbuf)[threadIdx.x];
          if (v != 0.f)
            atomicAdd(&gsum[(size_t)((sel == 0) ? gA : gB)*C_HID + ch2], v);
        }
      }
    } else {
      float sc[4];
      #pragma unroll
      for (int r = 0; r < 4; ++r){
        int row = m0 + q*4 + r;
        sc[r] = (FP8OUT && row < M) ? scale[row] * 64.f : 1.0f;
      }
      #pragma unroll
      for (int t = 0; t < 8; ++t){
        float bv = bias[t*16 + ln];
        #pragma unroll
        for (int r = 0; r < 4; ++r){
          int row = m0 + q*4 + r;
          if (row < M){
            float v = acc[t][r] + bv;
            v = v > 0.f ? v : 0.f;
            if (FP8OUT){
              v *= sc[r];
              int p = __builtin_amdgcn_cvt_pk_fp8_f32(v, v, 0, false);
              ((unsigned char*)outv)[(size_t)row*128 + t*16 + ln] = (unsigned char)(p & 0xFF);
            } else {
              ((unsigned short*)outv)[(size_t)row*128 + t*16 + ln] = f2bf(v);
            }
          }
        }
      }
    }
  }
}

// ---------- final: out[g] = (gsum[g]/cnt_g) @ Wlin + blin (64 parallel blocks) --------
__device__ __forceinline__ int lower_bound_i(const int* arr, int n, int val){
  int lo = 0, hi = n;
  while (lo < hi){ int mid = (lo + hi) >> 1; if (arr[mid] < val) lo = mid + 1; else hi = mid; }
  return lo;
}

__global__ void k_fin(const float* __restrict__ gsum, const int* __restrict__ batch,
                      const float* __restrict__ Wl, const float* __restrict__ bl,
                      float* __restrict__ out, int N){
  __shared__ float srow[C_HID];
  int g = blockIdx.x, t = threadIdx.x;      // 128 threads
  srow[t] = gsum[(size_t)g*C_HID + t];
  __syncthreads();
  if (t < COUT){
    int rs = clampi(lower_bound_i(batch, N, g), 0, N);
    int re = clampi(lower_bound_i(batch, N, g + 1), rs, N);
    float inv = 1.0f / fmaxf((float)(re - rs), 1.0f);
    float o = 0.f;
    for (int k = 0; k < 128; ++k)
      o += srow[k] * Wl[k*COUT + t];
    out[g*COUT + t] = o * inv + bl[t];
  }
}

extern "C" void kernel_launch(void* const* d_in, const int* in_sizes, int n_in,
                              void* d_out, int out_size, void* d_ws, size_t ws_size,
                              hipStream_t stream){
  const float* x0 = (const float*)d_in[0];
  const int* ei   = (const int*)d_in[1];
  const int* batch= (const int*)d_in[2];
  const float* W1 = (const float*)d_in[3];
  const float* b1 = (const float*)d_in[4];
  const float* W2 = (const float*)d_in[5];
  const float* b2 = (const float*)d_in[6];
  const float* W3 = (const float*)d_in[7];
  const float* b3 = (const float*)d_in[8];
  const float* Wl = (const float*)d_in[9];
  const float* bl = (const float*)d_in[10];
  float* out = (float*)d_out;

  int E = in_sizes[1] / 2;
  int N = in_sizes[2];
  const int* src = ei;
  const int* dst = ei + E;
  int NBUK = (N + BKT - 1) / BKT;
  int chunk = (E + NBLK - 1) / NBLK;
  int ncnt = NBUK * NBLK;
  int nsb  = (ncnt + SCAN_CH - 1) / SCAN_CH;   // scan blocks

  size_t off_acc = 0;
  auto carve = [&](size_t bytes)->size_t{
    size_t r = off_acc; off_acc += (bytes + 255) & ~(size_t)255; return r;
  };
  size_t o_cnt   = carve((size_t)ncnt*4);
  size_t o_bases = carve((size_t)(ncnt+1)*4);
  size_t o_bsum  = carve(256*4);
  size_t o_bbase = carve(256*4);
  size_t o_offs  = carve((size_t)(N+1)*4);
  size_t o_dinv  = carve((size_t)N*4);
  size_t o_meta  = carve((size_t)E*4);                      // compact CSR src list
  size_t o_rec   = carve((size_t)E*4);                      // bucket-sorted records
  size_t o_yA    = carve((size_t)(N+1)*C_HID);              // fp8 ping (+ zero row N)
  size_t o_yB    = carve((size_t)(N+1)*C_HID);              // fp8 pong (+ zero row N)
  size_t o_aggb  = carve((size_t)N*C_HID*2);                // bf16 agg
  size_t o_wt    = carve((size_t)3*128*128*2);              // bf16 Wt x3
  size_t o_gsum  = carve((size_t)NGRAPH*C_HID*4);           // pooled sums (f32)
  size_t need = off_acc;

  if (ws_size < need || NBUK > NBUK_MAX || nsb > 256){
    k_zero<<<(out_size+255)/256, 256, 0, stream>>>(out, out_size);
    return;
  }

  char* base = (char*)d_ws;
  int* cntg  = (int*)(base + o_cnt);
  int* bases = (int*)(base + o_bases);
  int* bsum  = (int*)(base + o_bsum);
  int* bbase = (int*)(base + o_bbase);
  int* offs  = (int*)(base + o_offs);
  float* dinv= (float*)(base + o_dinv);
  int* meta  = (int*)(base + o_meta);
  unsigned int* rec   = (unsigned int*)(base + o_rec);
  unsigned short* yA  = (unsigned short*)(base + o_yA);     // fp8 pairs as ushort
  unsigned short* yB  = (unsigned short*)(base + o_yB);
  unsigned int* aggb  = (unsigned int*)(base + o_aggb);
  unsigned short* wt  = (unsigned short*)(base + o_wt);
  float* gsum         = (float*)(base + o_gsum);

  k_cnt  <<<NBLK, 256, 0, stream>>>(dst, cntg, E, N, NBUK, chunk);
  k_scanA<<<nsb, 256, 0, stream>>>(cntg, bsum, ncnt);
  k_scanB<<<1, 256, 0, stream>>>(bsum, bbase, bases, nsb, ncnt);
  k_scanC<<<nsb, 256, 0, stream>>>(cntg, bbase, bases, ncnt);
  k_scat <<<NBLK, 256, 0, stream>>>(src, dst, bases, rec, E, N, NBUK, chunk);
  k_csr  <<<NBUK, BKT, 0, stream>>>(rec, bases, offs, dinv, meta, E, N, NBUK);

  int xg = (N*64 + 64 + 255)/256;
  k_prepx<<<xg, 256, 0, stream>>>((const float2*)x0, dinv, yA, yB,
                                  W1, W2, W3, wt, gsum, N);

  int spmm_grid = (N + 31) / 32;   // 4 waves/block, 8 nodes per wave

  k_spmm<<<spmm_grid, 256, 0, stream>>>(yA, offs, dinv, meta, aggb, N);
  k_gemm<true , false><<<GEMM_BLOCKS, 256, 0, stream>>>((const unsigned short*)aggb, wt,
      b1, dinv, (void*)yB, nullptr, nullptr, N);
  k_spmm<<<spmm_grid, 256, 0, stream>>>(yB, offs, dinv, meta, aggb, N);
  k_gemm<true , false><<<GEMM_BLOCKS, 256, 0, stream>>>((const unsigned short*)aggb, wt + 16384,
      b2, dinv, (void*)yA, nullptr, nullptr, N);
  k_spmm<<<spmm_grid, 256, 0, stream>>>(yA, offs, dinv, meta, aggb, N);
  k_gemm<false, true ><<<GEMM_BLOCKS, 256, 0, stream>>>((const unsigned short*)aggb, wt + 2*16384,
      b3, dinv, nullptr, batch, gsum, N);

  k_fin<<<NGRAPH, 128, 0, stream>>>(gsum, batch, Wl, bl, out, N);
}